// Round 3
// baseline (305.345 us; speedup 1.0000x reference)
//
#include <hip/hip_runtime.h>

// HollywoodFFT: B=4096 rows of N=4096 complex FFT (split re/im fp32).
// Radix-16 x 3 passes. R5 = R4 + persistent-block row pipeline:
//  - Grid = 1024 blocks x 256 thr; each block processes 4 rows (grid-stride).
//    4 blocks/CU resident (32KB LDS each), zero dispatch churn, perfect balance.
//  - Cross-row PREFETCH: the 32 global dword loads for row r+G are issued
//    right after row r's pass-A LDS writes; they complete while passes B/C
//    run (~2 barriers of LDS+VALU work). Global latency exposed only on the
//    first row per block. This attacks the R4 latency-bound signature
//    (VALU 28% / HBM 26% / all pipes idle).
//  - Row-invariant twiddle bases (__sincosf for pass B/C) hoisted out of the
//    row loop.
//  - All register-array indices remain compile-time constants (R3 lesson).
// n = a + 16b + 256c ; k = u + 16v + 256w (digits in [0,16)):
//   S1[a][b][u] = DFT16_c x[a+16b+256c]
//   S2 = S1 * W256^{b u}          (applied on pass-B read)
//   S3[a][u][v] = DFT16_b S2
//   S4 = S3 * W4096^{a(u+16v)}    (applied on pass-C read)
//   X[u+16v+256w] = DFT16_a S4
// LDS layouts (complex float2 slots, 32 KB):
//   L1: slot(a,b,u) = a     + 16*(b^u) + 256*u   (A-write / B-read)
//   L2: slot(a,u,v) = (a^u) + 16*(u^v) + 256*v   (B-write / C-read)
// Conflict-freedom (slot%16 distinct within each 16-lane group):
//   A-write: lanes a=0..15, (b,u) fixed -> col = a        : distinct
//   B-read : lanes a=0..15, (u,bb) fixed -> col = a       : distinct
//   B-write: lanes a=0..15, (u,v) fixed -> col = a^u      : distinct
//   C-read : lanes u2=0..15, (v2,aa) fixed -> col = aa^u2 : distinct
// Barriers per row: L1-ready, B-reads-done, L2-ready, C-reads-done (the last
// also fences LDS reuse by the next row's L1 writes).

#define NFFT 4096

__device__ __forceinline__ void fft16(float xr[16], float xi[16]) {
    // natural-order in/out 16-point DFT: bit-rev permute + 4 radix-2 DIT stages
    const int br[16] = {0,8,4,12,2,10,6,14,1,9,5,13,3,11,7,15};
    float yr[16], yi[16];
#pragma unroll
    for (int j = 0; j < 16; ++j) { yr[j] = xr[br[j]]; yi[j] = xi[br[j]]; }
    const float W16r[8] = { 1.0f,  0.92387953251128675613f,  0.70710678118654752440f,
                            0.38268343236508977173f,  0.0f, -0.38268343236508977173f,
                           -0.70710678118654752440f, -0.92387953251128675613f };
    const float W16i[8] = { 0.0f, -0.38268343236508977173f, -0.70710678118654752440f,
                           -0.92387953251128675613f, -1.0f, -0.92387953251128675613f,
                           -0.70710678118654752440f, -0.38268343236508977173f };
#pragma unroll
    for (int s = 0; s < 4; ++s) {
        const int stride = 1 << s;
        const int tm = 8 >> s;
#pragma unroll
        for (int g = 0; g < 16; g += 2 * stride) {
#pragma unroll
            for (int p = 0; p < stride; ++p) {
                const int i0 = g + p, i1 = i0 + stride;
                const float twr = W16r[p * tm], twi = W16i[p * tm];
                const float brr = yr[i1] * twr - yi[i1] * twi;
                const float bii = yr[i1] * twi + yi[i1] * twr;
                const float ar = yr[i0], ai = yi[i0];
                yr[i0] = ar + brr; yi[i0] = ai + bii;
                yr[i1] = ar - brr; yi[i1] = ai - bii;
            }
        }
    }
#pragma unroll
    for (int j = 0; j < 16; ++j) { xr[j] = yr[j]; xi[j] = yi[j]; }
}

__global__ __launch_bounds__(256, 4)
void HollywoodFFT_53584011985637_kernel(const float* __restrict__ xre,
                                        const float* __restrict__ xim,
                                        float* __restrict__ outre,
                                        float* __restrict__ outim,
                                        int B) {
    __shared__ __align__(16) float2 l[NFFT];   // 32 KB

    const int t = threadIdx.x;
    const int a = t & 15;   // low digit of thread id
    const int h = t >> 4;   // high digit: b in pass A, u in pass B, v2 in pass C

    // Row-invariant twiddle bases (hoisted out of the row loop):
    float sB, cB;   // W256^h      (pass-B recurrence step)
    __sincosf(-6.28318530717958647692f * (float)h * (1.0f / 256.0f), &sB, &cB);
    float sC, cC;   // W4096^t     (pass-C recurrence step; u2+16*v2 == t)
    __sincosf(-6.28318530717958647692f * (float)t * (1.0f / 4096.0f), &sC, &cC);

    const int G = gridDim.x;
    int row = blockIdx.x;

    // ---- Prologue: load first row into pf regs (latency exposed once) ----
    float pr[16], pi[16];
    {
        const float* __restrict__ xr_row = xre + (long long)row * NFFT;
        const float* __restrict__ xi_row = xim + (long long)row * NFFT;
#pragma unroll
        for (int c = 0; c < 16; ++c) {
            pr[c] = xr_row[t + 256 * c];
            pi[c] = xi_row[t + 256 * c];
        }
    }

    while (row < B) {
        const int next = row + G;

        // ---- Pass A: DFT16 over c on prefetched regs; write L1 ----
        fft16(pr, pi);
#pragma unroll
        for (int uu = 0; uu < 16; ++uu) {   // L1: a + 16*(b^u) + 256*u  (b = h)
            l[a + 16 * (h ^ uu) + 256 * uu] = make_float2(pr[uu], pi[uu]);
        }

        // ---- Issue prefetch for next row (hidden under passes B and C) ----
        if (next < B) {
            const float* __restrict__ xr_row = xre + (long long)next * NFFT;
            const float* __restrict__ xi_row = xim + (long long)next * NFFT;
#pragma unroll
            for (int c = 0; c < 16; ++c) {
                pr[c] = xr_row[t + 256 * c];
                pi[c] = xi_row[t + 256 * c];
            }
        }
        __syncthreads();                 // L1 ready

        // ---- Pass B: thread (a, u=h). Twiddle W256^{bu}, DFT16 over b ----
        float vr[16], vi[16];
        {
            float twr = 1.0f, twi = 0.0f;
#pragma unroll
            for (int bb = 0; bb < 16; ++bb) {
                const float2 xv = l[a + 16 * (bb ^ h) + 256 * h];
                vr[bb] = xv.x * twr - xv.y * twi;
                vi[bb] = xv.x * twi + xv.y * twr;
                const float ntr = twr * cB - twi * sB;
                twi = twr * sB + twi * cB;
                twr = ntr;
            }
        }
        fft16(vr, vi);
        __syncthreads();                 // all L1 reads done before L2 writes
#pragma unroll
        for (int v = 0; v < 16; ++v) {   // L2: (a^u) + 16*(u^v) + 256*v
            l[(a ^ h) + 16 * (h ^ v) + 256 * v] = make_float2(vr[v], vi[v]);
        }
        __syncthreads();                 // L2 ready

        // ---- Pass C: thread (u2=a, v2=h). Twiddle W4096^{aa*t}, DFT16 over a ----
        {
            float twr = 1.0f, twi = 0.0f;
#pragma unroll
            for (int aa = 0; aa < 16; ++aa) {
                const float2 xv = l[(aa ^ a) + 16 * (a ^ h) + 256 * h];
                vr[aa] = xv.x * twr - xv.y * twi;
                vi[aa] = xv.x * twi + xv.y * twr;
                const float ntr = twr * cC - twi * sC;
                twi = twr * sC + twi * cC;
                twr = ntr;
            }
        }
        __syncthreads();                 // all L2 reads done -> LDS reusable
                                         // (next row's L1 writes are fenced)
        fft16(vr, vi);

        float* __restrict__ or_row = outre + (long long)row * NFFT;
        float* __restrict__ oi_row = outim + (long long)row * NFFT;
#pragma unroll
        for (int w = 0; w < 16; ++w) {   // k = u2 + 16*v2 + 256*w = t + 256*w
            __builtin_nontemporal_store(vr[w], or_row + t + 256 * w);
            __builtin_nontemporal_store(vi[w], oi_row + t + 256 * w);
        }

        row = next;
    }
}

extern "C" void kernel_launch(void* const* d_in, const int* in_sizes, int n_in,
                              void* d_out, int out_size, void* d_ws, size_t ws_size,
                              hipStream_t stream) {
    const float* xre = (const float*)d_in[0];
    const float* xim = (const float*)d_in[1];
    const int B = in_sizes[0] / NFFT;            // 4096 rows
    float* out = (float*)d_out;
    float* outre = out;
    float* outim = out + (size_t)B * NFFT;       // outputs concatenated flat
    const int G = (B >= 1024) ? 1024 : B;        // 4 rows/block at B=4096
    HollywoodFFT_53584011985637_kernel<<<dim3(G), dim3(256), 0, stream>>>(
        xre, xim, outre, outim, B);
}

// Round 4
// 303.621 us; speedup vs baseline: 1.0057x; 1.0057x over previous
//
#include <hip/hip_runtime.h>

// HollywoodFFT: B=4096 rows of N=4096 complex FFT (split re/im fp32).
// Radix-16 x 3 passes. R6 = R5 with both R5 failure modes fixed:
//  - RAW BARRIERS (lgkmcnt-only): __syncthreads() emits
//    `s_waitcnt vmcnt(0) lgkmcnt(0); s_barrier`, which DRAINED the cross-row
//    prefetch at the first barrier (made it void). All per-row barriers only
//    protect LDS ordering, so we use `s_waitcnt lgkmcnt(0); s_barrier;
//    sched_barrier(0)` and let the prefetch's global loads stay in flight
//    across passes B/C (counted-vmcnt principle). The compiler inserts the
//    vmcnt wait at the next-row use of pr/pi.
//  - amdgpu_waves_per_eu(4,4): R5's allocator targeted the 64-VGPR/8-wave bin
//    and SPILLED the prefetch regs to scratch (VGPR_Count=64, +131MB FETCH /
//    +107MB WRITE of pure scratch traffic). Pinning to 4 waves/EU gives the
//    128-VGPR bin; peak live set ~110 fits with zero scratch.
//  - Residency: LDS 32KB -> 5 blocks/CU possible, VGPR bin -> 4 blocks/CU.
//    Grid = 1024 persistent blocks, 4 rows each; rows 2-4 have their global
//    loads fully hidden under the previous row's B/C passes.
// n = a + 16b + 256c ; k = u + 16v + 256w (digits in [0,16)):
//   S1[a][b][u] = DFT16_c x[a+16b+256c]
//   S2 = S1 * W256^{b u}          (applied on pass-B read)
//   S3[a][u][v] = DFT16_b S2
//   S4 = S3 * W4096^{a(u+16v)}    (applied on pass-C read)
//   X[u+16v+256w] = DFT16_a S4
// LDS layouts (complex float2 slots, 32 KB):
//   L1: slot(a,b,u) = a     + 16*(b^u) + 256*u   (A-write / B-read)
//   L2: slot(a,u,v) = (a^u) + 16*(u^v) + 256*v   (B-write / C-read)
// Conflict-freedom (slot%16 distinct within each 16-lane group):
//   A-write: lanes a=0..15, (b,u) fixed -> col = a        : distinct
//   B-read : lanes a=0..15, (u,bb) fixed -> col = a       : distinct
//   B-write: lanes a=0..15, (u,v) fixed -> col = a^u      : distinct
//   C-read : lanes u2=0..15, (v2,aa) fixed -> col = aa^u2 : distinct
// All register-array indices are compile-time constants (R3 lesson).

#define NFFT 4096

// LDS-only barrier: waits own-wave LDS ops, then s_barrier. Does NOT drain
// vmcnt, so global prefetch loads survive. sched_barrier stops the scheduler
// from hoisting anything across (guide rule #18).
#define LDS_BARRIER()                                          \
    do {                                                       \
        asm volatile("s_waitcnt lgkmcnt(0)" ::: "memory");     \
        __builtin_amdgcn_s_barrier();                          \
        __builtin_amdgcn_sched_barrier(0);                     \
    } while (0)

__device__ __forceinline__ void fft16(float xr[16], float xi[16]) {
    // natural-order in/out 16-point DFT: bit-rev permute + 4 radix-2 DIT stages
    const int br[16] = {0,8,4,12,2,10,6,14,1,9,5,13,3,11,7,15};
    float yr[16], yi[16];
#pragma unroll
    for (int j = 0; j < 16; ++j) { yr[j] = xr[br[j]]; yi[j] = xi[br[j]]; }
    const float W16r[8] = { 1.0f,  0.92387953251128675613f,  0.70710678118654752440f,
                            0.38268343236508977173f,  0.0f, -0.38268343236508977173f,
                           -0.70710678118654752440f, -0.92387953251128675613f };
    const float W16i[8] = { 0.0f, -0.38268343236508977173f, -0.70710678118654752440f,
                           -0.92387953251128675613f, -1.0f, -0.92387953251128675613f,
                           -0.70710678118654752440f, -0.38268343236508977173f };
#pragma unroll
    for (int s = 0; s < 4; ++s) {
        const int stride = 1 << s;
        const int tm = 8 >> s;
#pragma unroll
        for (int g = 0; g < 16; g += 2 * stride) {
#pragma unroll
            for (int p = 0; p < stride; ++p) {
                const int i0 = g + p, i1 = i0 + stride;
                const float twr = W16r[p * tm], twi = W16i[p * tm];
                const float brr = yr[i1] * twr - yi[i1] * twi;
                const float bii = yr[i1] * twi + yi[i1] * twr;
                const float ar = yr[i0], ai = yi[i0];
                yr[i0] = ar + brr; yi[i0] = ai + bii;
                yr[i1] = ar - brr; yi[i1] = ai - bii;
            }
        }
    }
#pragma unroll
    for (int j = 0; j < 16; ++j) { xr[j] = yr[j]; xi[j] = yi[j]; }
}

__global__ __launch_bounds__(256)
__attribute__((amdgpu_waves_per_eu(4, 4)))   // pin 128-VGPR bin: no spill
void HollywoodFFT_53584011985637_kernel(const float* __restrict__ xre,
                                        const float* __restrict__ xim,
                                        float* __restrict__ outre,
                                        float* __restrict__ outim,
                                        int B) {
    __shared__ __align__(16) float2 l[NFFT];   // 32 KB

    const int t = threadIdx.x;
    const int a = t & 15;   // low digit of thread id
    const int h = t >> 4;   // high digit: b in pass A, u in pass B, v2 in pass C

    // Row-invariant twiddle bases (hoisted out of the row loop):
    float sB, cB;   // W256^h      (pass-B recurrence step)
    __sincosf(-6.28318530717958647692f * (float)h * (1.0f / 256.0f), &sB, &cB);
    float sC, cC;   // W4096^t     (pass-C recurrence step; u2+16*v2 == t)
    __sincosf(-6.28318530717958647692f * (float)t * (1.0f / 4096.0f), &sC, &cC);

    const int G = gridDim.x;
    int row = blockIdx.x;

    // ---- Prologue: load first row into pf regs (latency exposed once) ----
    float pr[16], pi[16];
    {
        const float* __restrict__ xr_row = xre + (long long)row * NFFT;
        const float* __restrict__ xi_row = xim + (long long)row * NFFT;
#pragma unroll
        for (int c = 0; c < 16; ++c) {
            pr[c] = xr_row[t + 256 * c];
            pi[c] = xi_row[t + 256 * c];
        }
    }

    while (row < B) {
        const int next = row + G;

        // ---- Pass A: DFT16 over c on prefetched regs; write L1 ----
        fft16(pr, pi);
#pragma unroll
        for (int uu = 0; uu < 16; ++uu) {   // L1: a + 16*(b^u) + 256*u  (b = h)
            l[a + 16 * (h ^ uu) + 256 * uu] = make_float2(pr[uu], pi[uu]);
        }

        // ---- Issue prefetch for next row; stays in flight across the
        //      lgkm-only barriers, consumed at next iteration's pass A ----
        if (next < B) {
            const float* __restrict__ xr_row = xre + (long long)next * NFFT;
            const float* __restrict__ xi_row = xim + (long long)next * NFFT;
#pragma unroll
            for (int c = 0; c < 16; ++c) {
                pr[c] = xr_row[t + 256 * c];
                pi[c] = xi_row[t + 256 * c];
            }
        }
        LDS_BARRIER();                   // L1 ready (lgkm only, vmcnt alive)

        // ---- Pass B: thread (a, u=h). Twiddle W256^{bu}, DFT16 over b ----
        float vr[16], vi[16];
        {
            float twr = 1.0f, twi = 0.0f;
#pragma unroll
            for (int bb = 0; bb < 16; ++bb) {
                const float2 xv = l[a + 16 * (bb ^ h) + 256 * h];
                vr[bb] = xv.x * twr - xv.y * twi;
                vi[bb] = xv.x * twi + xv.y * twr;
                const float ntr = twr * cB - twi * sB;
                twi = twr * sB + twi * cB;
                twr = ntr;
            }
        }
        fft16(vr, vi);
        LDS_BARRIER();                   // all L1 reads done before L2 writes
#pragma unroll
        for (int v = 0; v < 16; ++v) {   // L2: (a^u) + 16*(u^v) + 256*v
            l[(a ^ h) + 16 * (h ^ v) + 256 * v] = make_float2(vr[v], vi[v]);
        }
        LDS_BARRIER();                   // L2 ready

        // ---- Pass C: thread (u2=a, v2=h). Twiddle W4096^{aa*t}, DFT16 over a ----
        {
            float twr = 1.0f, twi = 0.0f;
#pragma unroll
            for (int aa = 0; aa < 16; ++aa) {
                const float2 xv = l[(aa ^ a) + 16 * (a ^ h) + 256 * h];
                vr[aa] = xv.x * twr - xv.y * twi;
                vi[aa] = xv.x * twi + xv.y * twr;
                const float ntr = twr * cC - twi * sC;
                twi = twr * sC + twi * cC;
                twr = ntr;
            }
        }
        LDS_BARRIER();                   // all L2 reads done -> LDS reusable
        fft16(vr, vi);

        float* __restrict__ or_row = outre + (long long)row * NFFT;
        float* __restrict__ oi_row = outim + (long long)row * NFFT;
#pragma unroll
        for (int w = 0; w < 16; ++w) {   // k = u2 + 16*v2 + 256*w = t + 256*w
            __builtin_nontemporal_store(vr[w], or_row + t + 256 * w);
            __builtin_nontemporal_store(vi[w], oi_row + t + 256 * w);
        }

        row = next;
    }
}

extern "C" void kernel_launch(void* const* d_in, const int* in_sizes, int n_in,
                              void* d_out, int out_size, void* d_ws, size_t ws_size,
                              hipStream_t stream) {
    const float* xre = (const float*)d_in[0];
    const float* xim = (const float*)d_in[1];
    const int B = in_sizes[0] / NFFT;            // 4096 rows
    float* out = (float*)d_out;
    float* outre = out;
    float* outim = out + (size_t)B * NFFT;       // outputs concatenated flat
    const int G = (B >= 1024) ? 1024 : B;        // 4 rows/block at B=4096
    HollywoodFFT_53584011985637_kernel<<<dim3(G), dim3(256), 0, stream>>>(
        xre, xim, outre, outim, B);
}

// Round 6
// 238.747 us; speedup vs baseline: 1.2789x; 1.2717x over previous
//
#include <hip/hip_runtime.h>

// HollywoodFFT: B=4096 rows of N=4096 complex FFT (split re/im fp32).
// Radix-16 x 3 passes. R8 = R7 resubmitted (R7 run died broker-side with no
// compile/test diagnostic; audit found no barrier-divergence or race path —
// see theory notes). Structure:
//  - Cross-row prefetch WITHOUT register pressure: next row staged into a
//    second LDS buffer via __builtin_amdgcn_global_load_lds (zero VGPR cost).
//    R5/R6 held it in 32 VGPRs; allocator pinned 64-VGPR bin and spilled
//    (~+118MB FETCH / +91MB WRITE of scratch HBM traffic at VGPR_Count=64).
//  - Stage buffer PLANAR natural order: global_load_lds writes wave-uniform
//    base + lane*16; chunk q of wave w lands at float index 256w+1024q+4*lane,
//    matching global fvec4 index t+256q. Compute buffer keeps the proven
//    XOR-swizzled interleaved float2 L1/L2 layouts.
//  - Prefetch issued right after the L1-ready barrier, lands during passes
//    B+C; the end-of-row barrier is the ONLY vmcnt(0) wait (prefetch has had
//    ~2000+ cycles -> wait ~free). NT stores issued AFTER that fence overlap
//    the next row's pass A and drain at the NEXT end-of-row wait.
//  - Mid-row barriers are lgkmcnt-only (vmcnt survives across them).
//  - LDS 64KB/block -> 2 blocks/CU; grid = 512 persistent blocks x 8 rows.
//  - All register-array indices compile-time (R3 lesson: per-lane runtime
//    indices into reg arrays lower to cmp+cndmask chains).
// n = a + 16b + 256c ; k = u + 16v + 256w (digits in [0,16)):
//   S1[a][b][u] = DFT16_c x[a+16b+256c]
//   S2 = S1 * W256^{b u}          (applied on pass-B read)
//   S3[a][u][v] = DFT16_b S2
//   S4 = S3 * W4096^{a(u+16v)}    (applied on pass-C read)
//   X[u+16v+256w] = DFT16_a S4
// LDS:
//   bufS: planar s_re[4096], s_im[4096] natural order (stage-in; b32 reads,
//         2-way bank aliasing = free per m136)
//   bufC: float2[4096];  L1: a + 16*(b^u) + 256*u     (A-write / B-read)
//                        L2: (a^u) + 16*(u^v) + 256*v (B-write / C-read)
//   (slot%16 distinct within every 16-lane group on all bufC accesses)

#define NFFT 4096

// LDS-only barrier: waits own-wave LDS ops, then s_barrier. Does NOT drain
// vmcnt, so in-flight global_load_lds prefetch and NT stores survive.
#define LDS_BARRIER()                                          \
    do {                                                       \
        asm volatile("s_waitcnt lgkmcnt(0)" ::: "memory");     \
        __builtin_amdgcn_s_barrier();                          \
        __builtin_amdgcn_sched_barrier(0);                     \
    } while (0)

// Full barrier: drains vmcnt (prefetch arrival fence) + lgkm, then barrier.
#define FULL_BARRIER()                                                 \
    do {                                                               \
        asm volatile("s_waitcnt vmcnt(0) lgkmcnt(0)" ::: "memory");    \
        __builtin_amdgcn_s_barrier();                                  \
        __builtin_amdgcn_sched_barrier(0);                             \
    } while (0)

__device__ __forceinline__ void gl_lds16(const float* g, float* l) {
    // 16B-per-lane async global->LDS. LDS dest = wave-uniform base + lane*16.
    __builtin_amdgcn_global_load_lds(
        (const __attribute__((address_space(1))) void*)g,
        (__attribute__((address_space(3))) void*)l, 16, 0, 0);
}

__device__ __forceinline__ void stage_row(const float* __restrict__ xr_row,
                                          const float* __restrict__ xi_row,
                                          float* s_re, float* s_im, int t) {
    const int w = t >> 6;   // wave id (uniform within wave)
#pragma unroll
    for (int q = 0; q < 4; ++q) {
        // global floats [4t+1024q .. +3] -> s_* float index 256w+1024q+4*lane
        gl_lds16(xr_row + 4 * t + 1024 * q, s_re + 256 * w + 1024 * q);
        gl_lds16(xi_row + 4 * t + 1024 * q, s_im + 256 * w + 1024 * q);
    }
}

__device__ __forceinline__ void fft16(float xr[16], float xi[16]) {
    // natural-order in/out 16-point DFT: bit-rev permute + 4 radix-2 DIT stages
    const int br[16] = {0,8,4,12,2,10,6,14,1,9,5,13,3,11,7,15};
    float yr[16], yi[16];
#pragma unroll
    for (int j = 0; j < 16; ++j) { yr[j] = xr[br[j]]; yi[j] = xi[br[j]]; }
    const float W16r[8] = { 1.0f,  0.92387953251128675613f,  0.70710678118654752440f,
                            0.38268343236508977173f,  0.0f, -0.38268343236508977173f,
                           -0.70710678118654752440f, -0.92387953251128675613f };
    const float W16i[8] = { 0.0f, -0.38268343236508977173f, -0.70710678118654752440f,
                           -0.92387953251128675613f, -1.0f, -0.92387953251128675613f,
                           -0.70710678118654752440f, -0.38268343236508977173f };
#pragma unroll
    for (int s = 0; s < 4; ++s) {
        const int stride = 1 << s;
        const int tm = 8 >> s;
#pragma unroll
        for (int g = 0; g < 16; g += 2 * stride) {
#pragma unroll
            for (int p = 0; p < stride; ++p) {
                const int i0 = g + p, i1 = i0 + stride;
                const float twr = W16r[p * tm], twi = W16i[p * tm];
                const float brr = yr[i1] * twr - yi[i1] * twi;
                const float bii = yr[i1] * twi + yi[i1] * twr;
                const float ar = yr[i0], ai = yi[i0];
                yr[i0] = ar + brr; yi[i0] = ai + bii;
                yr[i1] = ar - brr; yi[i1] = ai - bii;
            }
        }
    }
#pragma unroll
    for (int j = 0; j < 16; ++j) { xr[j] = yr[j]; xi[j] = yi[j]; }
}

__global__ __launch_bounds__(256, 2)
void HollywoodFFT_53584011985637_kernel(const float* __restrict__ xre,
                                        const float* __restrict__ xim,
                                        float* __restrict__ outre,
                                        float* __restrict__ outim,
                                        int B) {
    __shared__ __align__(16) float2 bufC[NFFT];   // 32 KB compute (L1/L2)
    __shared__ __align__(16) float  s_re[NFFT];   // 16 KB stage re (planar)
    __shared__ __align__(16) float  s_im[NFFT];   // 16 KB stage im (planar)

    const int t = threadIdx.x;
    const int a = t & 15;   // low digit of thread id
    const int h = t >> 4;   // high digit: b in pass A, u in pass B, v2 in pass C

    // Row-invariant twiddle bases (hoisted out of the row loop):
    float sB, cB;   // W256^h   (pass-B recurrence step)
    __sincosf(-6.28318530717958647692f * (float)h * (1.0f / 256.0f), &sB, &cB);
    float sC, cC;   // W4096^t  (pass-C recurrence step; u2+16*v2 == t)
    __sincosf(-6.28318530717958647692f * (float)t * (1.0f / 4096.0f), &sC, &cC);

    const int G = gridDim.x;
    int row = blockIdx.x;

    // ---- Prologue: stage first row into bufS (latency exposed once/block) ----
    stage_row(xre + (long long)row * NFFT, xim + (long long)row * NFFT,
              s_re, s_im, t);
    FULL_BARRIER();

    while (row < B) {
        const int next = row + G;

        // ---- Pass A: read planar stage (b32, conflict-free), DFT16 over c,
        //      write interleaved L1 into bufC ----
        float vr[16], vi[16];
#pragma unroll
        for (int c = 0; c < 16; ++c) {
            vr[c] = s_re[t + 256 * c];
            vi[c] = s_im[t + 256 * c];
        }
        fft16(vr, vi);
#pragma unroll
        for (int uu = 0; uu < 16; ++uu) {   // L1: a + 16*(b^u) + 256*u  (b = h)
            bufC[a + 16 * (h ^ uu) + 256 * uu] = make_float2(vr[uu], vi[uu]);
        }
        LDS_BARRIER();                   // A-reads of bufS done + L1 ready

        // ---- Issue async prefetch of next row into bufS; lands during B+C ----
        if (next < B) {
            stage_row(xre + (long long)next * NFFT, xim + (long long)next * NFFT,
                      s_re, s_im, t);
        }

        // ---- Pass B: thread (a, u=h). Twiddle W256^{bu}, DFT16 over b ----
        {
            float twr = 1.0f, twi = 0.0f;
#pragma unroll
            for (int bb = 0; bb < 16; ++bb) {
                const float2 xv = bufC[a + 16 * (bb ^ h) + 256 * h];
                vr[bb] = xv.x * twr - xv.y * twi;
                vi[bb] = xv.x * twi + xv.y * twr;
                const float ntr = twr * cB - twi * sB;
                twi = twr * sB + twi * cB;
                twr = ntr;
            }
        }
        fft16(vr, vi);
        LDS_BARRIER();                   // all L1 reads done before L2 writes
#pragma unroll
        for (int v = 0; v < 16; ++v) {   // L2: (a^u) + 16*(u^v) + 256*v
            bufC[(a ^ h) + 16 * (h ^ v) + 256 * v] = make_float2(vr[v], vi[v]);
        }
        LDS_BARRIER();                   // L2 ready

        // ---- Pass C: thread (u2=a, v2=h). Twiddle W4096^{aa*t}, DFT16 over a ----
        {
            float twr = 1.0f, twi = 0.0f;
#pragma unroll
            for (int aa = 0; aa < 16; ++aa) {
                const float2 xv = bufC[(aa ^ a) + 16 * (a ^ h) + 256 * h];
                vr[aa] = xv.x * twr - xv.y * twi;
                vi[aa] = xv.x * twi + xv.y * twr;
                const float ntr = twr * cC - twi * sC;
                twi = twr * sC + twi * cC;
                twr = ntr;
            }
        }
        fft16(vr, vi);

        // ---- End-of-row: prefetch arrival + C-reads-done + bufS/bufC reuse
        //      fence. vmcnt(0) here waits loads issued ~2 passes ago (and the
        //      PREVIOUS row's NT stores, issued a full row ago) -> ~free. ----
        FULL_BARRIER();

        // ---- NT stores after the fence: overlap next row's pass A ----
        float* __restrict__ or_row = outre + (long long)row * NFFT;
        float* __restrict__ oi_row = outim + (long long)row * NFFT;
#pragma unroll
        for (int w = 0; w < 16; ++w) {   // k = u2 + 16*v2 + 256*w = t + 256*w
            __builtin_nontemporal_store(vr[w], or_row + t + 256 * w);
            __builtin_nontemporal_store(vi[w], oi_row + t + 256 * w);
        }

        row = next;
    }
}

extern "C" void kernel_launch(void* const* d_in, const int* in_sizes, int n_in,
                              void* d_out, int out_size, void* d_ws, size_t ws_size,
                              hipStream_t stream) {
    const float* xre = (const float*)d_in[0];
    const float* xim = (const float*)d_in[1];
    const int B = in_sizes[0] / NFFT;            // 4096 rows
    float* out = (float*)d_out;
    float* outre = out;
    float* outim = out + (size_t)B * NFFT;       // outputs concatenated flat
    const int G = (B >= 512) ? 512 : B;          // 8 rows/block, 2 blocks/CU
    HollywoodFFT_53584011985637_kernel<<<dim3(G), dim3(256), 0, stream>>>(
        xre, xim, outre, outim, B);
}